// Round 8
// baseline (130.782 us; speedup 1.0000x reference)
//
#include <hip/hip_runtime.h>

// Capped simplex projection: per row, w = clip(z - tau, 0, u), sum(w) = 1.
// One wave (64 lanes) per row; 64 fp32 elements per lane in registers.
//
// R7 = R6 + the n_free==0 guard:
//  - When n_free == 0 at tau0 (~7% of rows for Gaussian data: no z falls in
//    the width-u window), the reference's refined tau is a garbage value that
//    it never uses -- its write is purely classification-based. R6's
//    med3(z - tau) write used that garbage tau => full-cap errors. Now:
//    nf_i > 0 (wave-uniform)  -> med3(z - tau) fast write (provably within
//                                eps+delta of reference),
//    nf_i == 0                -> exact classification-based write (u / 0).

#define N_ASSETS 4096
#define N_SAMPLES 16384
#define MAX_W 0.02f
#define EPS 1e-7f
#define P1_ITERS 9
#define FB_ITERS 18          // fallback full-scan iterations
#define MS_ROUNDS 3          // multisection rounds (6 bits each)

typedef __attribute__((ext_vector_type(2))) float f32x2;

#define PKADD(d, a, b) asm("v_pk_add_f32 %0, %1, %2" : "=v"(d) : "v"(a), "v"(b))
#define PKMUL(d, a, b) asm("v_pk_mul_f32 %0, %1, %2" : "=v"(d) : "v"(a), "v"(b))

__device__ __forceinline__ float clipu(float v) {
    return __builtin_amdgcn_fmed3f(v, 0.0f, MAX_W);
}

__device__ __forceinline__ float bc_int_as_f(int v) {
    union { int i; float f; } u; u.i = v; return u.f;
}
__device__ __forceinline__ int bc_f_as_int(float v) {
    union { int i; float f; } u; u.f = v; return u.i;
}

// DPP-based wave64 reductions (ctrl codes must be compile-time constants).
template <int CTRL, int RMASK, bool BC>
__device__ __forceinline__ float dpp_add_step(float x) {
    int t = __builtin_amdgcn_update_dpp(0, bc_f_as_int(x), CTRL, RMASK, 0xF, BC);
    return x + bc_int_as_f(t);
}
__device__ __forceinline__ float wave_sum(float v) {
    v = dpp_add_step<0x111, 0xF, true>(v);   // row_shr:1
    v = dpp_add_step<0x112, 0xF, true>(v);   // row_shr:2
    v = dpp_add_step<0x114, 0xF, true>(v);   // row_shr:4
    v = dpp_add_step<0x118, 0xF, true>(v);   // row_shr:8
    v = dpp_add_step<0x142, 0xA, false>(v);  // row_bcast:15
    v = dpp_add_step<0x143, 0xC, false>(v);  // row_bcast:31
    return bc_int_as_f(__builtin_amdgcn_readlane(bc_f_as_int(v), 63));
}
template <int CTRL, int RMASK>
__device__ __forceinline__ float dpp_min_step(float x) {
    int xi = bc_f_as_int(x);
    int t = __builtin_amdgcn_update_dpp(xi, xi, CTRL, RMASK, 0xF, false);
    return fminf(x, bc_int_as_f(t));
}
template <int CTRL, int RMASK>
__device__ __forceinline__ float dpp_max_step(float x) {
    int xi = bc_f_as_int(x);
    int t = __builtin_amdgcn_update_dpp(xi, xi, CTRL, RMASK, 0xF, false);
    return fmaxf(x, bc_int_as_f(t));
}
__device__ __forceinline__ float wave_min(float v) {
    v = dpp_min_step<0x111, 0xF>(v); v = dpp_min_step<0x112, 0xF>(v);
    v = dpp_min_step<0x114, 0xF>(v); v = dpp_min_step<0x118, 0xF>(v);
    v = dpp_min_step<0x142, 0xA>(v); v = dpp_min_step<0x143, 0xC>(v);
    return bc_int_as_f(__builtin_amdgcn_readlane(bc_f_as_int(v), 63));
}
__device__ __forceinline__ float wave_max(float v) {
    v = dpp_max_step<0x111, 0xF>(v); v = dpp_max_step<0x112, 0xF>(v);
    v = dpp_max_step<0x114, 0xF>(v); v = dpp_max_step<0x118, 0xF>(v);
    v = dpp_max_step<0x142, 0xA>(v); v = dpp_max_step<0x143, 0xC>(v);
    return bc_int_as_f(__builtin_amdgcn_readlane(bc_f_as_int(v), 63));
}

// Full packed scan: sum of clip(z - mid) over 32 pairs.
__device__ __forceinline__ float scan_sum(const f32x2* zp, float mid) {
    f32x2 nm; nm.x = -mid; nm.y = -mid;
    f32x2 acc0 = {0.f, 0.f}, acc1 = {0.f, 0.f}, acc2 = {0.f, 0.f}, acc3 = {0.f, 0.f};
    #pragma unroll
    for (int k = 0; k < 32; k += 4) {
        f32x2 t0, t1, t2, t3;
        PKADD(t0, zp[k+0], nm);
        PKADD(t1, zp[k+1], nm);
        PKADD(t2, zp[k+2], nm);
        PKADD(t3, zp[k+3], nm);
        t0.x = clipu(t0.x); t0.y = clipu(t0.y);
        t1.x = clipu(t1.x); t1.y = clipu(t1.y);
        t2.x = clipu(t2.x); t2.y = clipu(t2.y);
        t3.x = clipu(t3.x); t3.y = clipu(t3.y);
        PKADD(acc0, acc0, t0);
        PKADD(acc1, acc1, t1);
        PKADD(acc2, acc2, t2);
        PKADD(acc3, acc3, t3);
    }
    PKADD(acc0, acc0, acc1);
    PKADD(acc2, acc2, acc3);
    PKADD(acc0, acc0, acc2);
    return acc0.x + acc0.y;
}

__global__ __launch_bounds__(256) void sparsemax_alloc_kernel(
    const float* __restrict__ x,
    const float* __restrict__ temperature,
    float* __restrict__ out) {

    __shared__ float amb_lds[4][16];

    const int wave = threadIdx.x >> 6;          // 4 waves per block
    const int lane = threadIdx.x & 63;
    const int row  = blockIdx.x * 4 + wave;
    if (row >= N_SAMPLES) return;

    const float4* xr   = reinterpret_cast<const float4*>(x + (size_t)row * N_ASSETS);
    float4*       outr = reinterpret_cast<float4*>(out + (size_t)row * N_ASSETS);

    const float rt = 1.0f / temperature[row];
    f32x2 rt2; rt2.x = rt; rt2.y = rt;

    // Load 64 elements/lane as 16 coalesced float4s; z = x / temp (packed mul).
    f32x2 zp[32];
    #pragma unroll
    for (int k = 0; k < 16; ++k) {
        float4 v = xr[k * 64 + lane];
        f32x2 lohalf, hihalf;
        lohalf.x = v.x; lohalf.y = v.y;
        hihalf.x = v.z; hihalf.y = v.w;
        PKMUL(zp[2*k],   lohalf, rt2);
        PKMUL(zp[2*k+1], hihalf, rt2);
    }

    // Row min/max.
    float mn = zp[0].x, mx = zp[0].x;
    #pragma unroll
    for (int k = 0; k < 32; ++k) {
        mn = fminf(mn, fminf(zp[k].x, zp[k].y));
        mx = fmaxf(mx, fmaxf(zp[k].x, zp[k].y));
    }
    mn = wave_min(mn);
    mx = wave_max(mx);

    float lo = mn - 1.0f;
    float hi = mx;

    // ---- Phase 1: full-scan bisection (packed) ----
    for (int it = 0; it < P1_ITERS; ++it) {
        const float mid = 0.5f * (lo + hi);
        const float s = wave_sum(scan_sum(zp, mid));
        const bool too_big = s > 1.0f;
        lo = too_big ? mid : lo;
        hi = too_big ? hi : mid;
    }

    // ---- Split: classify vs [lo, hi]; all future taus lie in (lo, hi] ----
    const float hi_pu = hi + MAX_W;
    const float lo_pu = lo + MAX_W;
    float sfree0 = 0.0f, sfree1 = 0.0f;
    int capcnt = 0, freecnt = 0;
    float za = lo, zb = lo, zc = lo;
    int cnt = 0;
    #pragma unroll
    for (int k = 0; k < 32; ++k) {
        #pragma unroll
        for (int c = 0; c < 2; ++c) {
            const float v = (c == 0) ? zp[k].x : zp[k].y;
            const bool isCap  = v >= hi_pu;
            const bool isFree = (v > hi) && (v < lo_pu);
            const bool isZero = v <= lo;
            capcnt  += __popcll(__ballot(isCap));
            freecnt += __popcll(__ballot(isFree));
            if (c) sfree1 += isFree ? v : 0.0f;
            else   sfree0 += isFree ? v : 0.0f;
            const bool isAmb = !(isZero || isCap || isFree);
            if (isAmb) {
                za = (cnt == 0) ? v : za;
                zb = (cnt == 1) ? v : zb;
                zc = (cnt == 2) ? v : zc;
                ++cnt;
            }
        }
    }
    const float At = (float)freecnt;   // ballot totals are wave-wide already
    const float Ct = fmaf((float)capcnt, MAX_W, wave_sum(sfree0 + sfree1));

    // Compact ambiguous values into wave-private LDS (16 slots).
    const unsigned long long b1 = __ballot(cnt >= 1);
    const unsigned long long b2 = __ballot(cnt >= 2);
    const unsigned long long b3 = __ballot(cnt >= 3);
    const unsigned long long b4 = __ballot(cnt >= 4);
    int off = __builtin_amdgcn_mbcnt_hi((unsigned)(b1 >> 32),
              __builtin_amdgcn_mbcnt_lo((unsigned)b1, 0));
    off    += __builtin_amdgcn_mbcnt_hi((unsigned)(b2 >> 32),
              __builtin_amdgcn_mbcnt_lo((unsigned)b2, 0));
    off    += __builtin_amdgcn_mbcnt_hi((unsigned)(b3 >> 32),
              __builtin_amdgcn_mbcnt_lo((unsigned)b3, 0));
    const int M = __popcll(b1) + __popcll(b2) + __popcll(b3);

    if (cnt >= 1 && off     < 16) amb_lds[wave][off]     = za;
    if (cnt >= 2 && off + 1 < 16) amb_lds[wave][off + 1] = zb;
    if (cnt >= 3 && off + 2 < 16) amb_lds[wave][off + 2] = zc;
    asm volatile("s_waitcnt lgkmcnt(0)" ::: "memory");

    const bool fast_ok = (b4 == 0ULL) && (M <= 16);

    // ---- Phase 2 ----
    if (fast_ok) {
        // Hoist up to 16 taps (8 packed pairs); absent slots -> lo (contributes 0).
        f32x2 a2[8];
        #pragma unroll
        for (int i = 0; i < 8; ++i) {
            const float u0 = (2*i     < M) ? amb_lds[wave][2*i]     : lo;
            const float u1 = (2*i + 1 < M) ? amb_lds[wave][2*i + 1] : lo;
            a2[i].x = u0; a2[i].y = u1;
        }
        // 64-way multisection on the closed form; one ballot per round.
        #pragma unroll
        for (int r = 0; r < MS_ROUNDS; ++r) {
            const float step = (hi - lo) * 0.015625f;
            const float tl = fmaf((float)(lane + 1), step, lo);
            f32x2 ntl; ntl.x = -tl; ntl.y = -tl;
            f32x2 acc0 = {0.f, 0.f}, acc1 = {0.f, 0.f};
            #pragma unroll
            for (int i = 0; i < 8; i += 2) {
                f32x2 t0, t1;
                PKADD(t0, a2[i],   ntl);
                PKADD(t1, a2[i+1], ntl);
                t0.x = clipu(t0.x); t0.y = clipu(t0.y);
                t1.x = clipu(t1.x); t1.y = clipu(t1.y);
                PKADD(acc0, acc0, t0);
                PKADD(acc1, acc1, t1);
            }
            PKADD(acc0, acc0, acc1);
            const float s = fmaf(-At, tl, Ct) + (acc0.x + acc0.y);
            const unsigned long long mask = __ballot(s > 1.0f);
            int j = __popcll(mask);
            j = (j > 63) ? 63 : j;
            const float lo_old = lo;
            lo = fmaf((float)j, step, lo_old);
            hi = fmaf((float)(j + 1), step, lo_old);
        }
    } else {
        for (int it = 0; it < FB_ITERS; ++it) {
            const float mid = 0.5f * (lo + hi);
            const float s = wave_sum(scan_sum(zp, mid));
            const bool too_big = s > 1.0f;
            lo = too_big ? mid : lo;
            hi = too_big ? hi : mid;
        }
    }
    const float tau0 = 0.5f * (lo + hi);

    // ---- Active set at tau0 (reference semantics); counts via ballot ----
    const float ucut = MAX_W - EPS;
    f32x2 nt0; nt0.x = -tau0; nt0.y = -tau0;
    float sf0 = 0.0f, sf1 = 0.0f;
    int nf_i = 0, nc_i = 0;
    #pragma unroll
    for (int k = 0; k < 32; k += 2) {
        f32x2 t0, t1;
        PKADD(t0, zp[k],   nt0);
        PKADD(t1, zp[k+1], nt0);
        const float wa = clipu(t0.x), wb = clipu(t0.y);
        const float wc = clipu(t1.x), wd = clipu(t1.y);
        const bool fa = (wa > EPS) && (wa < ucut);
        const bool fb = (wb > EPS) && (wb < ucut);
        const bool fc = (wc > EPS) && (wc < ucut);
        const bool fd = (wd > EPS) && (wd < ucut);
        sf0 += fa ? zp[k].x   : 0.0f;
        sf1 += fb ? zp[k].y   : 0.0f;
        sf0 += fc ? zp[k+1].x : 0.0f;
        sf1 += fd ? zp[k+1].y : 0.0f;
        nf_i += __popcll(__ballot(fa)) + __popcll(__ballot(fb))
              + __popcll(__ballot(fc)) + __popcll(__ballot(fd));
        nc_i += __popcll(__ballot(wa >= ucut)) + __popcll(__ballot(wb >= ucut))
              + __popcll(__ballot(wc >= ucut)) + __popcll(__ballot(wd >= ucut));
    }
    const float s_free = wave_sum(sf0 + sf1);
    const float tau = (s_free + MAX_W * (float)nc_i - 1.0f) / fmaxf((float)nf_i, 1.0f);

    if (nf_i > 0) {
        // ---- Fast final write: med3(z - tau, 0, u) ----
        // Valid when n_free >= 1: tau is KKT-consistent, so this matches the
        // reference within eps + |tau - tau0| (<< threshold).
        f32x2 ntau; ntau.x = -tau; ntau.y = -tau;
        #pragma unroll
        for (int k = 0; k < 16; ++k) {
            f32x2 t0, t1;
            PKADD(t0, zp[2*k],   ntau);
            PKADD(t1, zp[2*k+1], ntau);
            float4 o;
            o.x = clipu(t0.x); o.y = clipu(t0.y);
            o.z = clipu(t1.x); o.w = clipu(t1.y);
            outr[k * 64 + lane] = o;
        }
    } else {
        // ---- n_free == 0: reference ignores its (garbage) tau; write is
        // classification-based: capped -> u, else 0. ----
        #pragma unroll
        for (int k = 0; k < 16; ++k) {
            f32x2 t0, t1;
            PKADD(t0, zp[2*k],   nt0);
            PKADD(t1, zp[2*k+1], nt0);
            const float c0 = clipu(t0.x), c1 = clipu(t0.y);
            const float c2 = clipu(t1.x), c3 = clipu(t1.y);
            float4 o;
            o.x = (c0 >= ucut) ? MAX_W : 0.0f;
            o.y = (c1 >= ucut) ? MAX_W : 0.0f;
            o.z = (c2 >= ucut) ? MAX_W : 0.0f;
            o.w = (c3 >= ucut) ? MAX_W : 0.0f;
            outr[k * 64 + lane] = o;
        }
    }
}

extern "C" void kernel_launch(void* const* d_in, const int* in_sizes, int n_in,
                              void* d_out, int out_size, void* d_ws, size_t ws_size,
                              hipStream_t stream) {
    const float* x    = (const float*)d_in[0];
    const float* temp = (const float*)d_in[1];
    float* out = (float*)d_out;
    (void)in_sizes; (void)n_in; (void)out_size; (void)d_ws; (void)ws_size;

    dim3 grid(N_SAMPLES / 4);   // 4 rows (waves) per 256-thread block
    dim3 block(256);
    hipLaunchKernelGGL(sparsemax_alloc_kernel, grid, block, 0, stream, x, temp, out);
}

// Round 9
// 120.312 us; speedup vs baseline: 1.0870x; 1.0870x over previous
//
#include <hip/hip_runtime.h>

// Capped simplex projection: per row, w = clip(z - tau, 0, u), sum(w) = 1.
// One wave (64 lanes) per row; 64 fp32 elements per lane in registers.
//
// R8 changes vs R7 (count-bisection):
//  - P1 sum-bisection replaced by COUNT-bisection: since every w <= u and
//    sum(w)=1, N(t)=#{z>t}>=50 => tau* >= t-u, and N(t)<=49 => tau* <= t.
//    Bisect on N via ballot+popcount (1 v_cmp/elem, SALU accumulates) to a
//    0.014-wide count bracket => 0.034-wide tau bracket. No DPP reduces.
//  - With bracket width ~u the free band is empty: classification is
//    zero/cap/ambiguous only; s(tau) = capcnt*u + sum clip(amb - tau) EXACTLY.
//  - Epilogue (active set at tau0) evaluated over the <=16 register-resident
//    ambiguous taps only (wave-uniform scalar ops) instead of a 64-elem pass.
//  - Fallback (>16 amb total or >3 in one lane): 14 full sum-scan bisections
//    + full epilogue (correct for any data).

#define N_ASSETS 4096
#define N_SAMPLES 16384
#define MAX_W 0.02f
#define EPS 1e-7f
#define KRANK 50             // ceil(1 / MAX_W)
#define CNT_EPS 0.014f       // count-bisect stop width
#define FB_ITERS 14          // fallback sum-scan iterations (from 0.034 bracket)
#define MS_ROUNDS 3          // multisection rounds (6 bits each)

typedef __attribute__((ext_vector_type(2))) float f32x2;

#define PKADD(d, a, b) asm("v_pk_add_f32 %0, %1, %2" : "=v"(d) : "v"(a), "v"(b))
#define PKMUL(d, a, b) asm("v_pk_mul_f32 %0, %1, %2" : "=v"(d) : "v"(a), "v"(b))

__device__ __forceinline__ float clipu(float v) {
    return __builtin_amdgcn_fmed3f(v, 0.0f, MAX_W);
}

__device__ __forceinline__ float bc_int_as_f(int v) {
    union { int i; float f; } u; u.i = v; return u.f;
}
__device__ __forceinline__ int bc_f_as_int(float v) {
    union { int i; float f; } u; u.f = v; return u.i;
}

// DPP-based wave64 reductions (ctrl codes must be compile-time constants).
template <int CTRL, int RMASK, bool BC>
__device__ __forceinline__ float dpp_add_step(float x) {
    int t = __builtin_amdgcn_update_dpp(0, bc_f_as_int(x), CTRL, RMASK, 0xF, BC);
    return x + bc_int_as_f(t);
}
__device__ __forceinline__ float wave_sum(float v) {
    v = dpp_add_step<0x111, 0xF, true>(v);   // row_shr:1
    v = dpp_add_step<0x112, 0xF, true>(v);   // row_shr:2
    v = dpp_add_step<0x114, 0xF, true>(v);   // row_shr:4
    v = dpp_add_step<0x118, 0xF, true>(v);   // row_shr:8
    v = dpp_add_step<0x142, 0xA, false>(v);  // row_bcast:15
    v = dpp_add_step<0x143, 0xC, false>(v);  // row_bcast:31
    return bc_int_as_f(__builtin_amdgcn_readlane(bc_f_as_int(v), 63));
}
template <int CTRL, int RMASK>
__device__ __forceinline__ float dpp_min_step(float x) {
    int xi = bc_f_as_int(x);
    int t = __builtin_amdgcn_update_dpp(xi, xi, CTRL, RMASK, 0xF, false);
    return fminf(x, bc_int_as_f(t));
}
template <int CTRL, int RMASK>
__device__ __forceinline__ float dpp_max_step(float x) {
    int xi = bc_f_as_int(x);
    int t = __builtin_amdgcn_update_dpp(xi, xi, CTRL, RMASK, 0xF, false);
    return fmaxf(x, bc_int_as_f(t));
}
__device__ __forceinline__ float wave_min(float v) {
    v = dpp_min_step<0x111, 0xF>(v); v = dpp_min_step<0x112, 0xF>(v);
    v = dpp_min_step<0x114, 0xF>(v); v = dpp_min_step<0x118, 0xF>(v);
    v = dpp_min_step<0x142, 0xA>(v); v = dpp_min_step<0x143, 0xC>(v);
    return bc_int_as_f(__builtin_amdgcn_readlane(bc_f_as_int(v), 63));
}
__device__ __forceinline__ float wave_max(float v) {
    v = dpp_max_step<0x111, 0xF>(v); v = dpp_max_step<0x112, 0xF>(v);
    v = dpp_max_step<0x114, 0xF>(v); v = dpp_max_step<0x118, 0xF>(v);
    v = dpp_max_step<0x142, 0xA>(v); v = dpp_max_step<0x143, 0xC>(v);
    return bc_int_as_f(__builtin_amdgcn_readlane(bc_f_as_int(v), 63));
}

// Wave-uniform count of elements > t (exact; ballot is already wave-wide).
__device__ __forceinline__ int count_gt(const f32x2* zp, float t) {
    int c = 0;
    #pragma unroll
    for (int k = 0; k < 32; ++k) {
        c += __popcll(__ballot(zp[k].x > t));
        c += __popcll(__ballot(zp[k].y > t));
    }
    return c;
}

// Full packed scan: sum of clip(z - mid) over 32 pairs (fallback path only).
__device__ __forceinline__ float scan_sum(const f32x2* zp, float mid) {
    f32x2 nm; nm.x = -mid; nm.y = -mid;
    f32x2 acc0 = {0.f, 0.f}, acc1 = {0.f, 0.f}, acc2 = {0.f, 0.f}, acc3 = {0.f, 0.f};
    #pragma unroll
    for (int k = 0; k < 32; k += 4) {
        f32x2 t0, t1, t2, t3;
        PKADD(t0, zp[k+0], nm);
        PKADD(t1, zp[k+1], nm);
        PKADD(t2, zp[k+2], nm);
        PKADD(t3, zp[k+3], nm);
        t0.x = clipu(t0.x); t0.y = clipu(t0.y);
        t1.x = clipu(t1.x); t1.y = clipu(t1.y);
        t2.x = clipu(t2.x); t2.y = clipu(t2.y);
        t3.x = clipu(t3.x); t3.y = clipu(t3.y);
        PKADD(acc0, acc0, t0);
        PKADD(acc1, acc1, t1);
        PKADD(acc2, acc2, t2);
        PKADD(acc3, acc3, t3);
    }
    PKADD(acc0, acc0, acc1);
    PKADD(acc2, acc2, acc3);
    PKADD(acc0, acc0, acc2);
    return acc0.x + acc0.y;
}

__global__ __launch_bounds__(256) void sparsemax_alloc_kernel(
    const float* __restrict__ x,
    const float* __restrict__ temperature,
    float* __restrict__ out) {

    __shared__ float amb_lds[4][16];

    const int wave = threadIdx.x >> 6;          // 4 waves per block
    const int lane = threadIdx.x & 63;
    const int row  = blockIdx.x * 4 + wave;
    if (row >= N_SAMPLES) return;

    const float4* xr   = reinterpret_cast<const float4*>(x + (size_t)row * N_ASSETS);
    float4*       outr = reinterpret_cast<float4*>(out + (size_t)row * N_ASSETS);

    const float rt = 1.0f / temperature[row];
    f32x2 rt2; rt2.x = rt; rt2.y = rt;

    // Load 64 elements/lane as 16 coalesced float4s; z = x / temp (packed mul).
    f32x2 zp[32];
    #pragma unroll
    for (int k = 0; k < 16; ++k) {
        float4 v = xr[k * 64 + lane];
        f32x2 lohalf, hihalf;
        lohalf.x = v.x; lohalf.y = v.y;
        hihalf.x = v.z; hihalf.y = v.w;
        PKMUL(zp[2*k],   lohalf, rt2);
        PKMUL(zp[2*k+1], hihalf, rt2);
    }

    // Row min/max.
    float mn = zp[0].x, mx = zp[0].x;
    #pragma unroll
    for (int k = 0; k < 32; ++k) {
        mn = fminf(mn, fminf(zp[k].x, zp[k].y));
        mx = fmaxf(mx, fmaxf(zp[k].x, zp[k].y));
    }
    mn = wave_min(mn);
    mx = wave_max(mx);

    // ---- Count-bisection: find t-bracket with N(clo) >= 50, N(chi) <= 49 ----
    float clo = mn - 1.0f;   // N = 4096 >= 50
    float chi = mx;          // N = 0    <= 49
    for (int it = 0; it < 64; ++it) {
        if (!(chi - clo > CNT_EPS)) break;
        const float mid = 0.5f * (clo + chi);
        const int c = count_gt(zp, mid);
        const bool big = (c >= KRANK);
        clo = big ? mid : clo;
        chi = big ? chi : mid;
    }
    // tau* in (Lo, Hi], width <= CNT_EPS + u ~= 0.034.
    const float Lo = clo - MAX_W;
    const float Hi = chi;
    const float capTh = Hi + MAX_W;   // z >= capTh -> always capped on [Lo,Hi]

    // ---- Classify: zero (z<=Lo) / cap (z>=capTh) / ambiguous ----
    int capcnt = 0;
    float za = Lo, zb = Lo, zc = Lo;
    int cnt = 0;
    #pragma unroll
    for (int k = 0; k < 32; ++k) {
        #pragma unroll
        for (int c2 = 0; c2 < 2; ++c2) {
            const float v = (c2 == 0) ? zp[k].x : zp[k].y;
            capcnt += __popcll(__ballot(v >= capTh));
            const bool isAmb = (v > Lo) && (v < capTh);
            if (isAmb) {
                za = (cnt == 0) ? v : za;
                zb = (cnt == 1) ? v : zb;
                zc = (cnt == 2) ? v : zc;
                ++cnt;
            }
        }
    }
    const float capC = (float)capcnt * MAX_W;  // exact s-contribution of caps

    // Compact ambiguous values into wave-private LDS (16 slots).
    const unsigned long long b1 = __ballot(cnt >= 1);
    const unsigned long long b2 = __ballot(cnt >= 2);
    const unsigned long long b3 = __ballot(cnt >= 3);
    const unsigned long long b4 = __ballot(cnt >= 4);
    int off = __builtin_amdgcn_mbcnt_hi((unsigned)(b1 >> 32),
              __builtin_amdgcn_mbcnt_lo((unsigned)b1, 0));
    off    += __builtin_amdgcn_mbcnt_hi((unsigned)(b2 >> 32),
              __builtin_amdgcn_mbcnt_lo((unsigned)b2, 0));
    off    += __builtin_amdgcn_mbcnt_hi((unsigned)(b3 >> 32),
              __builtin_amdgcn_mbcnt_lo((unsigned)b3, 0));
    const int M = __popcll(b1) + __popcll(b2) + __popcll(b3);

    if (cnt >= 1 && off     < 16) amb_lds[wave][off]     = za;
    if (cnt >= 2 && off + 1 < 16) amb_lds[wave][off + 1] = zb;
    if (cnt >= 3 && off + 2 < 16) amb_lds[wave][off + 2] = zc;
    asm volatile("s_waitcnt lgkmcnt(0)" ::: "memory");

    const bool fast_ok = (b4 == 0ULL) && (M <= 16);

    float lo = Lo, hi = Hi;
    const float ucut = MAX_W - EPS;
    float tau, tau0;
    int nf_total;

    if (fast_ok) {
        // Hoist up to 16 taps (8 packed pairs); absent -> Lo (contributes 0,
        // never free/capped in the epilogue).
        f32x2 a2[8];
        #pragma unroll
        for (int i = 0; i < 8; ++i) {
            a2[i].x = (2*i     < M) ? amb_lds[wave][2*i]     : Lo;
            a2[i].y = (2*i + 1 < M) ? amb_lds[wave][2*i + 1] : Lo;
        }
        // 64-way multisection: s(tl) = capC + sum clip(a - tl); one ballot/round.
        #pragma unroll
        for (int r = 0; r < MS_ROUNDS; ++r) {
            const float step = (hi - lo) * 0.015625f;
            const float tl = fmaf((float)(lane + 1), step, lo);
            f32x2 ntl; ntl.x = -tl; ntl.y = -tl;
            f32x2 acc0 = {0.f, 0.f}, acc1 = {0.f, 0.f};
            #pragma unroll
            for (int i = 0; i < 8; i += 2) {
                f32x2 t0, t1;
                PKADD(t0, a2[i],   ntl);
                PKADD(t1, a2[i+1], ntl);
                t0.x = clipu(t0.x); t0.y = clipu(t0.y);
                t1.x = clipu(t1.x); t1.y = clipu(t1.y);
                PKADD(acc0, acc0, t0);
                PKADD(acc1, acc1, t1);
            }
            PKADD(acc0, acc0, acc1);
            const float s = capC + (acc0.x + acc0.y);
            const unsigned long long mask = __ballot(s > 1.0f);
            int j = __popcll(mask);
            j = (j > 63) ? 63 : j;
            const float lo_old = lo;
            lo = fmaf((float)j, step, lo_old);
            hi = fmaf((float)(j + 1), step, lo_old);
        }
        tau0 = 0.5f * (lo + hi);

        // ---- Epilogue over the 16 taps only (wave-uniform, no reduces) ----
        int nf = 0, ncap = capcnt;
        float sfree = 0.0f;
        #pragma unroll
        for (int i = 0; i < 8; ++i) {
            const float w0x = clipu(a2[i].x - tau0);
            const float w0y = clipu(a2[i].y - tau0);
            const bool fx = (w0x > EPS) && (w0x < ucut);
            const bool fy = (w0y > EPS) && (w0y < ucut);
            nf += fx ? 1 : 0;          nf += fy ? 1 : 0;
            sfree += fx ? a2[i].x : 0.0f;
            sfree += fy ? a2[i].y : 0.0f;
            ncap += (w0x >= ucut) ? 1 : 0;
            ncap += (w0y >= ucut) ? 1 : 0;
        }
        nf_total = nf;
        tau = (sfree + MAX_W * (float)ncap - 1.0f) / fmaxf((float)nf, 1.0f);
    } else {
        // ---- Fallback: sum-scan bisection on [Lo, Hi] ----
        for (int it = 0; it < FB_ITERS; ++it) {
            const float mid = 0.5f * (lo + hi);
            const float s = wave_sum(scan_sum(zp, mid));
            const bool too_big = s > 1.0f;
            lo = too_big ? mid : lo;
            hi = too_big ? hi : mid;
        }
        tau0 = 0.5f * (lo + hi);
        // Full active-set pass (ballot counts).
        f32x2 nt0; nt0.x = -tau0; nt0.y = -tau0;
        float sf0 = 0.0f, sf1 = 0.0f;
        int nf_i = 0, nc_i = 0;
        #pragma unroll
        for (int k = 0; k < 32; k += 2) {
            f32x2 t0, t1;
            PKADD(t0, zp[k],   nt0);
            PKADD(t1, zp[k+1], nt0);
            const float wa = clipu(t0.x), wb = clipu(t0.y);
            const float wc = clipu(t1.x), wd = clipu(t1.y);
            const bool fa = (wa > EPS) && (wa < ucut);
            const bool fb = (wb > EPS) && (wb < ucut);
            const bool fc = (wc > EPS) && (wc < ucut);
            const bool fd = (wd > EPS) && (wd < ucut);
            sf0 += fa ? zp[k].x   : 0.0f;
            sf1 += fb ? zp[k].y   : 0.0f;
            sf0 += fc ? zp[k+1].x : 0.0f;
            sf1 += fd ? zp[k+1].y : 0.0f;
            nf_i += __popcll(__ballot(fa)) + __popcll(__ballot(fb))
                  + __popcll(__ballot(fc)) + __popcll(__ballot(fd));
            nc_i += __popcll(__ballot(wa >= ucut)) + __popcll(__ballot(wb >= ucut))
                  + __popcll(__ballot(wc >= ucut)) + __popcll(__ballot(wd >= ucut));
        }
        const float s_free = wave_sum(sf0 + sf1);
        nf_total = nf_i;
        tau = (s_free + MAX_W * (float)nc_i - 1.0f) / fmaxf((float)nf_i, 1.0f);
    }

    if (nf_total > 0) {
        // ---- Fast final write: med3(z - tau, 0, u) (KKT-consistent tau) ----
        f32x2 ntau; ntau.x = -tau; ntau.y = -tau;
        #pragma unroll
        for (int k = 0; k < 16; ++k) {
            f32x2 t0, t1;
            PKADD(t0, zp[2*k],   ntau);
            PKADD(t1, zp[2*k+1], ntau);
            float4 o;
            o.x = clipu(t0.x); o.y = clipu(t0.y);
            o.z = clipu(t1.x); o.w = clipu(t1.y);
            outr[k * 64 + lane] = o;
        }
    } else {
        // ---- n_free == 0: reference ignores its tau; classification write ----
        const float capAt0 = tau0 + ucut;   // z - tau0 >= ucut  <=>  z >= capAt0
        #pragma unroll
        for (int k = 0; k < 16; ++k) {
            float4 o;
            o.x = (zp[2*k].x   >= capAt0) ? MAX_W : 0.0f;
            o.y = (zp[2*k].y   >= capAt0) ? MAX_W : 0.0f;
            o.z = (zp[2*k+1].x >= capAt0) ? MAX_W : 0.0f;
            o.w = (zp[2*k+1].y >= capAt0) ? MAX_W : 0.0f;
            outr[k * 64 + lane] = o;
        }
    }
}

extern "C" void kernel_launch(void* const* d_in, const int* in_sizes, int n_in,
                              void* d_out, int out_size, void* d_ws, size_t ws_size,
                              hipStream_t stream) {
    const float* x    = (const float*)d_in[0];
    const float* temp = (const float*)d_in[1];
    float* out = (float*)d_out;
    (void)in_sizes; (void)n_in; (void)out_size; (void)d_ws; (void)ws_size;

    dim3 grid(N_SAMPLES / 4);   // 4 rows (waves) per 256-thread block
    dim3 block(256);
    hipLaunchKernelGGL(sparsemax_alloc_kernel, grid, block, 0, stream, x, temp, out);
}

// Round 10
// 112.083 us; speedup vs baseline: 1.1668x; 1.0734x over previous
//
#include <hip/hip_runtime.h>

// Capped simplex projection: per row, w = clip(z - tau, 0, u), sum(w) = 1.
// One wave (64 lanes) per row; 64 fp32 elements per lane in registers.
//
// R9 changes vs R8:
//  - Count scans accumulate per-lane (v_cmp+v_addc, no SALU) + 1 DPP int
//    reduce, instead of ballot+popcount (2 SALU/elem on the CU-shared
//    scalar unit -- ~48us of serialized SALU at 64 waves/CU).
//  - Statistical bracket seeding: sigma_row via one packed sum(z^2) pass;
//    dual probe at {2.10, 2.40}*sigma (50th order stat = 2.247sigma +-
//    0.055sigma). Probe results update the bracket via invariant-preserving
//    max/min rules, so wrong seeds cost nothing (outer bracket mn-1/mx is
//    always valid). Bisect only to width 0.04*sigma (floor 2e-3).
//  - Tap capacity 16 -> 24 (4/lane) to support the wider stop bracket.
//  - ~5 count scans total vs R8's ~11. Fallback: 17 sum-scan bisections +
//    full epilogue (correct for any data).

#define N_ASSETS 4096
#define N_SAMPLES 16384
#define MAX_W 0.02f
#define EPS 1e-7f
#define KRANK 50             // ceil(1 / MAX_W)
#define FB_ITERS 17          // fallback sum-scan iterations
#define MS_ROUNDS 3          // multisection rounds (6 bits each)
#define NTAPS 24

typedef __attribute__((ext_vector_type(2))) float f32x2;

#define PKADD(d, a, b) asm("v_pk_add_f32 %0, %1, %2" : "=v"(d) : "v"(a), "v"(b))
#define PKMUL(d, a, b) asm("v_pk_mul_f32 %0, %1, %2" : "=v"(d) : "v"(a), "v"(b))
#define PKFMA(d, a, b, c) asm("v_pk_fma_f32 %0, %1, %2, %3" : "=v"(d) : "v"(a), "v"(b), "v"(c))

__device__ __forceinline__ float clipu(float v) {
    return __builtin_amdgcn_fmed3f(v, 0.0f, MAX_W);
}

__device__ __forceinline__ float bc_int_as_f(int v) {
    union { int i; float f; } u; u.i = v; return u.f;
}
__device__ __forceinline__ int bc_f_as_int(float v) {
    union { int i; float f; } u; u.f = v; return u.i;
}

// DPP-based wave64 reductions (ctrl codes must be compile-time constants).
template <int CTRL, int RMASK, bool BC>
__device__ __forceinline__ float dpp_add_step(float x) {
    int t = __builtin_amdgcn_update_dpp(0, bc_f_as_int(x), CTRL, RMASK, 0xF, BC);
    return x + bc_int_as_f(t);
}
__device__ __forceinline__ float wave_sum(float v) {
    v = dpp_add_step<0x111, 0xF, true>(v);   // row_shr:1
    v = dpp_add_step<0x112, 0xF, true>(v);   // row_shr:2
    v = dpp_add_step<0x114, 0xF, true>(v);   // row_shr:4
    v = dpp_add_step<0x118, 0xF, true>(v);   // row_shr:8
    v = dpp_add_step<0x142, 0xA, false>(v);  // row_bcast:15
    v = dpp_add_step<0x143, 0xC, false>(v);  // row_bcast:31
    return bc_int_as_f(__builtin_amdgcn_readlane(bc_f_as_int(v), 63));
}
template <int CTRL, int RMASK, bool BC>
__device__ __forceinline__ int dpp_iadd_step(int x) {
    int t = __builtin_amdgcn_update_dpp(0, x, CTRL, RMASK, 0xF, BC);
    return x + t;
}
__device__ __forceinline__ int wave_isum(int v) {
    v = dpp_iadd_step<0x111, 0xF, true>(v);
    v = dpp_iadd_step<0x112, 0xF, true>(v);
    v = dpp_iadd_step<0x114, 0xF, true>(v);
    v = dpp_iadd_step<0x118, 0xF, true>(v);
    v = dpp_iadd_step<0x142, 0xA, false>(v);
    v = dpp_iadd_step<0x143, 0xC, false>(v);
    return __builtin_amdgcn_readlane(v, 63);
}
template <int CTRL, int RMASK>
__device__ __forceinline__ float dpp_min_step(float x) {
    int xi = bc_f_as_int(x);
    int t = __builtin_amdgcn_update_dpp(xi, xi, CTRL, RMASK, 0xF, false);
    return fminf(x, bc_int_as_f(t));
}
template <int CTRL, int RMASK>
__device__ __forceinline__ float dpp_max_step(float x) {
    int xi = bc_f_as_int(x);
    int t = __builtin_amdgcn_update_dpp(xi, xi, CTRL, RMASK, 0xF, false);
    return fmaxf(x, bc_int_as_f(t));
}
__device__ __forceinline__ float wave_min(float v) {
    v = dpp_min_step<0x111, 0xF>(v); v = dpp_min_step<0x112, 0xF>(v);
    v = dpp_min_step<0x114, 0xF>(v); v = dpp_min_step<0x118, 0xF>(v);
    v = dpp_min_step<0x142, 0xA>(v); v = dpp_min_step<0x143, 0xC>(v);
    return bc_int_as_f(__builtin_amdgcn_readlane(bc_f_as_int(v), 63));
}
__device__ __forceinline__ float wave_max(float v) {
    v = dpp_max_step<0x111, 0xF>(v); v = dpp_max_step<0x112, 0xF>(v);
    v = dpp_max_step<0x114, 0xF>(v); v = dpp_max_step<0x118, 0xF>(v);
    v = dpp_max_step<0x142, 0xA>(v); v = dpp_max_step<0x143, 0xC>(v);
    return bc_int_as_f(__builtin_amdgcn_readlane(bc_f_as_int(v), 63));
}

// Count of elements > t across the wave (per-lane v_cmp+addc, 1 int reduce).
__device__ __forceinline__ int count_gt(const f32x2* zp, float t) {
    int c = 0;
    #pragma unroll
    for (int k = 0; k < 32; ++k) {
        c += (zp[k].x > t);
        c += (zp[k].y > t);
    }
    return wave_isum(c);
}

// Full packed scan: sum of clip(z - mid) over 32 pairs (fallback path only).
__device__ __forceinline__ float scan_sum(const f32x2* zp, float mid) {
    f32x2 nm; nm.x = -mid; nm.y = -mid;
    f32x2 acc0 = {0.f, 0.f}, acc1 = {0.f, 0.f}, acc2 = {0.f, 0.f}, acc3 = {0.f, 0.f};
    #pragma unroll
    for (int k = 0; k < 32; k += 4) {
        f32x2 t0, t1, t2, t3;
        PKADD(t0, zp[k+0], nm);
        PKADD(t1, zp[k+1], nm);
        PKADD(t2, zp[k+2], nm);
        PKADD(t3, zp[k+3], nm);
        t0.x = clipu(t0.x); t0.y = clipu(t0.y);
        t1.x = clipu(t1.x); t1.y = clipu(t1.y);
        t2.x = clipu(t2.x); t2.y = clipu(t2.y);
        t3.x = clipu(t3.x); t3.y = clipu(t3.y);
        PKADD(acc0, acc0, t0);
        PKADD(acc1, acc1, t1);
        PKADD(acc2, acc2, t2);
        PKADD(acc3, acc3, t3);
    }
    PKADD(acc0, acc0, acc1);
    PKADD(acc2, acc2, acc3);
    PKADD(acc0, acc0, acc2);
    return acc0.x + acc0.y;
}

__global__ __launch_bounds__(256) void sparsemax_alloc_kernel(
    const float* __restrict__ x,
    const float* __restrict__ temperature,
    float* __restrict__ out) {

    __shared__ float amb_lds[4][NTAPS];

    const int wave = threadIdx.x >> 6;          // 4 waves per block
    const int lane = threadIdx.x & 63;
    const int row  = blockIdx.x * 4 + wave;
    if (row >= N_SAMPLES) return;

    const float4* xr   = reinterpret_cast<const float4*>(x + (size_t)row * N_ASSETS);
    float4*       outr = reinterpret_cast<float4*>(out + (size_t)row * N_ASSETS);

    const float rt = 1.0f / temperature[row];
    f32x2 rt2; rt2.x = rt; rt2.y = rt;

    // Load 64 elements/lane as 16 coalesced float4s; z = x / temp (packed mul).
    f32x2 zp[32];
    #pragma unroll
    for (int k = 0; k < 16; ++k) {
        float4 v = xr[k * 64 + lane];
        f32x2 lohalf, hihalf;
        lohalf.x = v.x; lohalf.y = v.y;
        hihalf.x = v.z; hihalf.y = v.w;
        PKMUL(zp[2*k],   lohalf, rt2);
        PKMUL(zp[2*k+1], hihalf, rt2);
    }

    // Row min/max + sum of squares (one fused pass).
    float mn = zp[0].x, mx = zp[0].x;
    f32x2 ss0 = {0.f, 0.f}, ss1 = {0.f, 0.f};
    #pragma unroll
    for (int k = 0; k < 32; k += 2) {
        mn = fminf(mn, fminf(zp[k].x, zp[k].y));
        mx = fmaxf(mx, fmaxf(zp[k].x, zp[k].y));
        mn = fminf(mn, fminf(zp[k+1].x, zp[k+1].y));
        mx = fmaxf(mx, fmaxf(zp[k+1].x, zp[k+1].y));
        PKFMA(ss0, zp[k],   zp[k],   ss0);
        PKFMA(ss1, zp[k+1], zp[k+1], ss1);
    }
    mn = wave_min(mn);
    mx = wave_max(mx);
    PKADD(ss0, ss0, ss1);
    const float sig = sqrtf(wave_sum(ss0.x + ss0.y) * (1.0f / (float)N_ASSETS));

    // ---- Count-bisection with seeded probes ----
    float clo = mn - 1.0f;   // N = 4096 >= 50 guaranteed
    float chi = mx;          // N = 0    <= 49 guaranteed

    // Dual probe at the expected 50th order statistic (2.247 sigma) +- 0.15 sigma.
    {
        float t1 = 2.10f * sig, t2 = 2.40f * sig;
        t1 = fminf(fmaxf(t1, clo), chi);
        t2 = fminf(fmaxf(t2, t1), chi);
        int c1 = 0, c2 = 0;
        #pragma unroll
        for (int k = 0; k < 32; ++k) {
            c1 += (zp[k].x > t1); c1 += (zp[k].y > t1);
            c2 += (zp[k].x > t2); c2 += (zp[k].y > t2);
        }
        c1 = wave_isum(c1);
        c2 = wave_isum(c2);
        if (c1 >= KRANK) clo = fmaxf(clo, t1); else chi = fminf(chi, t1);
        if (c2 >= KRANK) clo = fmaxf(clo, t2); else chi = fminf(chi, t2);
    }

    const float stop_w = fmaxf(0.04f * sig, 2e-3f);
    for (int it = 0; it < 48; ++it) {
        if (!(chi - clo > stop_w)) break;
        const float mid = 0.5f * (clo + chi);
        const int c = count_gt(zp, mid);
        const bool big = (c >= KRANK);
        clo = big ? mid : clo;
        chi = big ? chi : mid;
    }
    // tau* in (Lo, Hi]; ambiguity band (Lo, capTh).
    const float Lo = clo - MAX_W;
    const float Hi = chi;
    const float capTh = Hi + MAX_W;

    // ---- Classify: zero (z<=Lo) / cap (z>=capTh) / ambiguous ----
    int capc = 0;
    float za = Lo, zb = Lo, zc = Lo, zd = Lo;
    int cnt = 0;
    #pragma unroll
    for (int k = 0; k < 32; ++k) {
        #pragma unroll
        for (int c2 = 0; c2 < 2; ++c2) {
            const float v = (c2 == 0) ? zp[k].x : zp[k].y;
            capc += (v >= capTh);
            const bool isAmb = (v > Lo) && (v < capTh);
            if (isAmb) {
                za = (cnt == 0) ? v : za;
                zb = (cnt == 1) ? v : zb;
                zc = (cnt == 2) ? v : zc;
                zd = (cnt == 3) ? v : zd;
                ++cnt;
            }
        }
    }
    const int capcnt = wave_isum(capc);
    const float capC = (float)capcnt * MAX_W;

    // Compact ambiguous values into wave-private LDS (NTAPS slots).
    const unsigned long long b1 = __ballot(cnt >= 1);
    const unsigned long long b2 = __ballot(cnt >= 2);
    const unsigned long long b3 = __ballot(cnt >= 3);
    const unsigned long long b4 = __ballot(cnt >= 4);
    const unsigned long long b5 = __ballot(cnt >= 5);
    int off = __builtin_amdgcn_mbcnt_hi((unsigned)(b1 >> 32),
              __builtin_amdgcn_mbcnt_lo((unsigned)b1, 0));
    off    += __builtin_amdgcn_mbcnt_hi((unsigned)(b2 >> 32),
              __builtin_amdgcn_mbcnt_lo((unsigned)b2, 0));
    off    += __builtin_amdgcn_mbcnt_hi((unsigned)(b3 >> 32),
              __builtin_amdgcn_mbcnt_lo((unsigned)b3, 0));
    off    += __builtin_amdgcn_mbcnt_hi((unsigned)(b4 >> 32),
              __builtin_amdgcn_mbcnt_lo((unsigned)b4, 0));
    const int M = __popcll(b1) + __popcll(b2) + __popcll(b3) + __popcll(b4);

    if (cnt >= 1 && off     < NTAPS) amb_lds[wave][off]     = za;
    if (cnt >= 2 && off + 1 < NTAPS) amb_lds[wave][off + 1] = zb;
    if (cnt >= 3 && off + 2 < NTAPS) amb_lds[wave][off + 2] = zc;
    if (cnt >= 4 && off + 3 < NTAPS) amb_lds[wave][off + 3] = zd;
    asm volatile("s_waitcnt lgkmcnt(0)" ::: "memory");

    const bool fast_ok = (b5 == 0ULL) && (M <= NTAPS);

    float lo = Lo, hi = Hi;
    const float ucut = MAX_W - EPS;
    float tau, tau0;
    int nf_total;

    if (fast_ok) {
        // Hoist up to NTAPS taps (12 packed pairs); absent -> Lo.
        f32x2 a2[NTAPS / 2];
        #pragma unroll
        for (int i = 0; i < NTAPS / 2; ++i) {
            a2[i].x = (2*i     < M) ? amb_lds[wave][2*i]     : Lo;
            a2[i].y = (2*i + 1 < M) ? amb_lds[wave][2*i + 1] : Lo;
        }
        // 64-way multisection: s(tl) = capC + sum clip(a - tl); one ballot/round.
        #pragma unroll
        for (int r = 0; r < MS_ROUNDS; ++r) {
            const float step = (hi - lo) * 0.015625f;
            const float tl = fmaf((float)(lane + 1), step, lo);
            f32x2 ntl; ntl.x = -tl; ntl.y = -tl;
            f32x2 acc0 = {0.f, 0.f}, acc1 = {0.f, 0.f};
            #pragma unroll
            for (int i = 0; i < NTAPS / 2; i += 2) {
                f32x2 t0, t1;
                PKADD(t0, a2[i],   ntl);
                PKADD(t1, a2[i+1], ntl);
                t0.x = clipu(t0.x); t0.y = clipu(t0.y);
                t1.x = clipu(t1.x); t1.y = clipu(t1.y);
                PKADD(acc0, acc0, t0);
                PKADD(acc1, acc1, t1);
            }
            PKADD(acc0, acc0, acc1);
            const float s = capC + (acc0.x + acc0.y);
            const unsigned long long mask = __ballot(s > 1.0f);
            int j = __popcll(mask);
            j = (j > 63) ? 63 : j;
            const float lo_old = lo;
            lo = fmaf((float)j, step, lo_old);
            hi = fmaf((float)(j + 1), step, lo_old);
        }
        tau0 = 0.5f * (lo + hi);

        // ---- Epilogue over the taps only (wave-uniform, no reduces) ----
        int nf = 0, ncap = capcnt;
        float sfree = 0.0f;
        #pragma unroll
        for (int i = 0; i < NTAPS / 2; ++i) {
            const float w0x = clipu(a2[i].x - tau0);
            const float w0y = clipu(a2[i].y - tau0);
            const bool fx = (w0x > EPS) && (w0x < ucut);
            const bool fy = (w0y > EPS) && (w0y < ucut);
            nf += fx ? 1 : 0;          nf += fy ? 1 : 0;
            sfree += fx ? a2[i].x : 0.0f;
            sfree += fy ? a2[i].y : 0.0f;
            ncap += (w0x >= ucut) ? 1 : 0;
            ncap += (w0y >= ucut) ? 1 : 0;
        }
        nf_total = nf;
        tau = (sfree + MAX_W * (float)ncap - 1.0f) / fmaxf((float)nf, 1.0f);
    } else {
        // ---- Fallback: sum-scan bisection on [Lo, Hi] ----
        for (int it = 0; it < FB_ITERS; ++it) {
            const float mid = 0.5f * (lo + hi);
            const float s = wave_sum(scan_sum(zp, mid));
            const bool too_big = s > 1.0f;
            lo = too_big ? mid : lo;
            hi = too_big ? hi : mid;
        }
        tau0 = 0.5f * (lo + hi);
        // Full active-set pass (per-lane counts + reduces).
        f32x2 nt0; nt0.x = -tau0; nt0.y = -tau0;
        float sf0 = 0.0f, sf1 = 0.0f;
        int nf_i = 0, nc_i = 0;
        #pragma unroll
        for (int k = 0; k < 32; k += 2) {
            f32x2 t0, t1;
            PKADD(t0, zp[k],   nt0);
            PKADD(t1, zp[k+1], nt0);
            const float wa = clipu(t0.x), wb = clipu(t0.y);
            const float wc = clipu(t1.x), wd = clipu(t1.y);
            const bool fa = (wa > EPS) && (wa < ucut);
            const bool fb = (wb > EPS) && (wb < ucut);
            const bool fc = (wc > EPS) && (wc < ucut);
            const bool fd = (wd > EPS) && (wd < ucut);
            sf0 += fa ? zp[k].x   : 0.0f;
            sf1 += fb ? zp[k].y   : 0.0f;
            sf0 += fc ? zp[k+1].x : 0.0f;
            sf1 += fd ? zp[k+1].y : 0.0f;
            nf_i += (fa ? 1 : 0) + (fb ? 1 : 0) + (fc ? 1 : 0) + (fd ? 1 : 0);
            nc_i += (wa >= ucut) + (wb >= ucut) + (wc >= ucut) + (wd >= ucut);
        }
        const float s_free = wave_sum(sf0 + sf1);
        nf_i = wave_isum(nf_i);
        nc_i = wave_isum(nc_i);
        nf_total = nf_i;
        tau = (s_free + MAX_W * (float)nc_i - 1.0f) / fmaxf((float)nf_i, 1.0f);
    }

    if (nf_total > 0) {
        // ---- Fast final write: med3(z - tau, 0, u) (KKT-consistent tau) ----
        f32x2 ntau; ntau.x = -tau; ntau.y = -tau;
        #pragma unroll
        for (int k = 0; k < 16; ++k) {
            f32x2 t0, t1;
            PKADD(t0, zp[2*k],   ntau);
            PKADD(t1, zp[2*k+1], ntau);
            float4 o;
            o.x = clipu(t0.x); o.y = clipu(t0.y);
            o.z = clipu(t1.x); o.w = clipu(t1.y);
            outr[k * 64 + lane] = o;
        }
    } else {
        // ---- n_free == 0: reference ignores its tau; classification write ----
        const float capAt0 = tau0 + ucut;
        #pragma unroll
        for (int k = 0; k < 16; ++k) {
            float4 o;
            o.x = (zp[2*k].x   >= capAt0) ? MAX_W : 0.0f;
            o.y = (zp[2*k].y   >= capAt0) ? MAX_W : 0.0f;
            o.z = (zp[2*k+1].x >= capAt0) ? MAX_W : 0.0f;
            o.w = (zp[2*k+1].y >= capAt0) ? MAX_W : 0.0f;
            outr[k * 64 + lane] = o;
        }
    }
}

extern "C" void kernel_launch(void* const* d_in, const int* in_sizes, int n_in,
                              void* d_out, int out_size, void* d_ws, size_t ws_size,
                              hipStream_t stream) {
    const float* x    = (const float*)d_in[0];
    const float* temp = (const float*)d_in[1];
    float* out = (float*)d_out;
    (void)in_sizes; (void)n_in; (void)out_size; (void)d_ws; (void)ws_size;

    dim3 grid(N_SAMPLES / 4);   // 4 rows (waves) per 256-thread block
    dim3 block(256);
    hipLaunchKernelGGL(sparsemax_alloc_kernel, grid, block, 0, stream, x, temp, out);
}

// Round 11
// 83.992 us; speedup vs baseline: 1.5571x; 1.3344x over previous
//
#include <hip/hip_runtime.h>

// Capped simplex projection: per row, w = clip(z - tau, 0, u), sum(w) = 1.
// One wave (64 lanes) per row; 64 fp32 elements per lane in registers.
//
// R10 changes vs R9:
//  - Non-temporal output stores (nt): the 256 MiB output stream was evicting
//    the 256 MiB input from the 256 MiB L3 every replay (FETCH pinned at
//    128 MiB). Streaming the write past the cache keeps x L3-resident.
//  - min/max/sum(z^2) fused into the load loop: each float4 is consumed as it
//    returns instead of load-all -> wait -> separate pass.
//  - Per-lane ambiguity cap 4 -> 3 (one fewer ballot + VGPR); NTAPS stays 24.

#define N_ASSETS 4096
#define N_SAMPLES 16384
#define MAX_W 0.02f
#define EPS 1e-7f
#define KRANK 50             // ceil(1 / MAX_W)
#define FB_ITERS 17          // fallback sum-scan iterations
#define MS_ROUNDS 3          // multisection rounds (6 bits each)
#define NTAPS 24

typedef __attribute__((ext_vector_type(2))) float f32x2;
typedef __attribute__((ext_vector_type(4))) float f32x4;

#define PKADD(d, a, b) asm("v_pk_add_f32 %0, %1, %2" : "=v"(d) : "v"(a), "v"(b))
#define PKMUL(d, a, b) asm("v_pk_mul_f32 %0, %1, %2" : "=v"(d) : "v"(a), "v"(b))
#define PKFMA(d, a, b, c) asm("v_pk_fma_f32 %0, %1, %2, %3" : "=v"(d) : "v"(a), "v"(b), "v"(c))

__device__ __forceinline__ float clipu(float v) {
    return __builtin_amdgcn_fmed3f(v, 0.0f, MAX_W);
}

__device__ __forceinline__ float bc_int_as_f(int v) {
    union { int i; float f; } u; u.i = v; return u.f;
}
__device__ __forceinline__ int bc_f_as_int(float v) {
    union { int i; float f; } u; u.f = v; return u.i;
}

// DPP-based wave64 reductions (ctrl codes must be compile-time constants).
template <int CTRL, int RMASK, bool BC>
__device__ __forceinline__ float dpp_add_step(float x) {
    int t = __builtin_amdgcn_update_dpp(0, bc_f_as_int(x), CTRL, RMASK, 0xF, BC);
    return x + bc_int_as_f(t);
}
__device__ __forceinline__ float wave_sum(float v) {
    v = dpp_add_step<0x111, 0xF, true>(v);   // row_shr:1
    v = dpp_add_step<0x112, 0xF, true>(v);   // row_shr:2
    v = dpp_add_step<0x114, 0xF, true>(v);   // row_shr:4
    v = dpp_add_step<0x118, 0xF, true>(v);   // row_shr:8
    v = dpp_add_step<0x142, 0xA, false>(v);  // row_bcast:15
    v = dpp_add_step<0x143, 0xC, false>(v);  // row_bcast:31
    return bc_int_as_f(__builtin_amdgcn_readlane(bc_f_as_int(v), 63));
}
template <int CTRL, int RMASK, bool BC>
__device__ __forceinline__ int dpp_iadd_step(int x) {
    int t = __builtin_amdgcn_update_dpp(0, x, CTRL, RMASK, 0xF, BC);
    return x + t;
}
__device__ __forceinline__ int wave_isum(int v) {
    v = dpp_iadd_step<0x111, 0xF, true>(v);
    v = dpp_iadd_step<0x112, 0xF, true>(v);
    v = dpp_iadd_step<0x114, 0xF, true>(v);
    v = dpp_iadd_step<0x118, 0xF, true>(v);
    v = dpp_iadd_step<0x142, 0xA, false>(v);
    v = dpp_iadd_step<0x143, 0xC, false>(v);
    return __builtin_amdgcn_readlane(v, 63);
}
template <int CTRL, int RMASK>
__device__ __forceinline__ float dpp_min_step(float x) {
    int xi = bc_f_as_int(x);
    int t = __builtin_amdgcn_update_dpp(xi, xi, CTRL, RMASK, 0xF, false);
    return fminf(x, bc_int_as_f(t));
}
template <int CTRL, int RMASK>
__device__ __forceinline__ float dpp_max_step(float x) {
    int xi = bc_f_as_int(x);
    int t = __builtin_amdgcn_update_dpp(xi, xi, CTRL, RMASK, 0xF, false);
    return fmaxf(x, bc_int_as_f(t));
}
__device__ __forceinline__ float wave_min(float v) {
    v = dpp_min_step<0x111, 0xF>(v); v = dpp_min_step<0x112, 0xF>(v);
    v = dpp_min_step<0x114, 0xF>(v); v = dpp_min_step<0x118, 0xF>(v);
    v = dpp_min_step<0x142, 0xA>(v); v = dpp_min_step<0x143, 0xC>(v);
    return bc_int_as_f(__builtin_amdgcn_readlane(bc_f_as_int(v), 63));
}
__device__ __forceinline__ float wave_max(float v) {
    v = dpp_max_step<0x111, 0xF>(v); v = dpp_max_step<0x112, 0xF>(v);
    v = dpp_max_step<0x114, 0xF>(v); v = dpp_max_step<0x118, 0xF>(v);
    v = dpp_max_step<0x142, 0xA>(v); v = dpp_max_step<0x143, 0xC>(v);
    return bc_int_as_f(__builtin_amdgcn_readlane(bc_f_as_int(v), 63));
}

// Count of elements > t across the wave (per-lane v_cmp+addc, 1 int reduce).
__device__ __forceinline__ int count_gt(const f32x2* zp, float t) {
    int c = 0;
    #pragma unroll
    for (int k = 0; k < 32; ++k) {
        c += (zp[k].x > t);
        c += (zp[k].y > t);
    }
    return wave_isum(c);
}

// Full packed scan: sum of clip(z - mid) over 32 pairs (fallback path only).
__device__ __forceinline__ float scan_sum(const f32x2* zp, float mid) {
    f32x2 nm; nm.x = -mid; nm.y = -mid;
    f32x2 acc0 = {0.f, 0.f}, acc1 = {0.f, 0.f}, acc2 = {0.f, 0.f}, acc3 = {0.f, 0.f};
    #pragma unroll
    for (int k = 0; k < 32; k += 4) {
        f32x2 t0, t1, t2, t3;
        PKADD(t0, zp[k+0], nm);
        PKADD(t1, zp[k+1], nm);
        PKADD(t2, zp[k+2], nm);
        PKADD(t3, zp[k+3], nm);
        t0.x = clipu(t0.x); t0.y = clipu(t0.y);
        t1.x = clipu(t1.x); t1.y = clipu(t1.y);
        t2.x = clipu(t2.x); t2.y = clipu(t2.y);
        t3.x = clipu(t3.x); t3.y = clipu(t3.y);
        PKADD(acc0, acc0, t0);
        PKADD(acc1, acc1, t1);
        PKADD(acc2, acc2, t2);
        PKADD(acc3, acc3, t3);
    }
    PKADD(acc0, acc0, acc1);
    PKADD(acc2, acc2, acc3);
    PKADD(acc0, acc0, acc2);
    return acc0.x + acc0.y;
}

__global__ __launch_bounds__(256) void sparsemax_alloc_kernel(
    const float* __restrict__ x,
    const float* __restrict__ temperature,
    float* __restrict__ out) {

    __shared__ float amb_lds[4][NTAPS];

    const int wave = threadIdx.x >> 6;          // 4 waves per block
    const int lane = threadIdx.x & 63;
    const int row  = blockIdx.x * 4 + wave;
    if (row >= N_SAMPLES) return;

    const float4* xr   = reinterpret_cast<const float4*>(x + (size_t)row * N_ASSETS);
    f32x4*        outr = reinterpret_cast<f32x4*>(out + (size_t)row * N_ASSETS);

    const float rt = 1.0f / temperature[row];
    f32x2 rt2; rt2.x = rt; rt2.y = rt;

    // Load 64 elements/lane (16 coalesced float4s); z = x/temp, and fuse the
    // min/max/sum(z^2) statistics pass so each float4 is consumed on return.
    f32x2 zp[32];
    float mn = 3.4e38f, mx = -3.4e38f;
    f32x2 ss0 = {0.f, 0.f}, ss1 = {0.f, 0.f};
    #pragma unroll
    for (int k = 0; k < 16; ++k) {
        float4 v = xr[k * 64 + lane];
        f32x2 lohalf, hihalf;
        lohalf.x = v.x; lohalf.y = v.y;
        hihalf.x = v.z; hihalf.y = v.w;
        PKMUL(zp[2*k],   lohalf, rt2);
        PKMUL(zp[2*k+1], hihalf, rt2);
        mn = fminf(mn, fminf(zp[2*k].x,   zp[2*k].y));
        mx = fmaxf(mx, fmaxf(zp[2*k].x,   zp[2*k].y));
        mn = fminf(mn, fminf(zp[2*k+1].x, zp[2*k+1].y));
        mx = fmaxf(mx, fmaxf(zp[2*k+1].x, zp[2*k+1].y));
        PKFMA(ss0, zp[2*k],   zp[2*k],   ss0);
        PKFMA(ss1, zp[2*k+1], zp[2*k+1], ss1);
    }
    mn = wave_min(mn);
    mx = wave_max(mx);
    PKADD(ss0, ss0, ss1);
    const float sig = sqrtf(wave_sum(ss0.x + ss0.y) * (1.0f / (float)N_ASSETS));

    // ---- Count-bisection with seeded probes ----
    float clo = mn - 1.0f;   // N = 4096 >= 50 guaranteed
    float chi = mx;          // N = 0    <= 49 guaranteed

    // Dual probe at the expected 50th order statistic (2.247 sigma) +- 0.15 sigma.
    {
        float t1 = 2.10f * sig, t2 = 2.40f * sig;
        t1 = fminf(fmaxf(t1, clo), chi);
        t2 = fminf(fmaxf(t2, t1), chi);
        int c1 = 0, c2 = 0;
        #pragma unroll
        for (int k = 0; k < 32; ++k) {
            c1 += (zp[k].x > t1); c1 += (zp[k].y > t1);
            c2 += (zp[k].x > t2); c2 += (zp[k].y > t2);
        }
        c1 = wave_isum(c1);
        c2 = wave_isum(c2);
        if (c1 >= KRANK) clo = fmaxf(clo, t1); else chi = fminf(chi, t1);
        if (c2 >= KRANK) clo = fmaxf(clo, t2); else chi = fminf(chi, t2);
    }

    const float stop_w = fmaxf(0.04f * sig, 2e-3f);
    for (int it = 0; it < 48; ++it) {
        if (!(chi - clo > stop_w)) break;
        const float mid = 0.5f * (clo + chi);
        const int c = count_gt(zp, mid);
        const bool big = (c >= KRANK);
        clo = big ? mid : clo;
        chi = big ? chi : mid;
    }
    // tau* in (Lo, Hi]; ambiguity band (Lo, capTh).
    const float Lo = clo - MAX_W;
    const float Hi = chi;
    const float capTh = Hi + MAX_W;

    // ---- Classify: zero (z<=Lo) / cap (z>=capTh) / ambiguous ----
    int capc = 0;
    float za = Lo, zb = Lo, zc = Lo;
    int cnt = 0;
    #pragma unroll
    for (int k = 0; k < 32; ++k) {
        #pragma unroll
        for (int c2 = 0; c2 < 2; ++c2) {
            const float v = (c2 == 0) ? zp[k].x : zp[k].y;
            capc += (v >= capTh);
            const bool isAmb = (v > Lo) && (v < capTh);
            if (isAmb) {
                za = (cnt == 0) ? v : za;
                zb = (cnt == 1) ? v : zb;
                zc = (cnt == 2) ? v : zc;
                ++cnt;
            }
        }
    }
    const int capcnt = wave_isum(capc);
    const float capC = (float)capcnt * MAX_W;

    // Compact ambiguous values into wave-private LDS (NTAPS slots).
    const unsigned long long b1 = __ballot(cnt >= 1);
    const unsigned long long b2 = __ballot(cnt >= 2);
    const unsigned long long b3 = __ballot(cnt >= 3);
    const unsigned long long b4 = __ballot(cnt >= 4);
    int off = __builtin_amdgcn_mbcnt_hi((unsigned)(b1 >> 32),
              __builtin_amdgcn_mbcnt_lo((unsigned)b1, 0));
    off    += __builtin_amdgcn_mbcnt_hi((unsigned)(b2 >> 32),
              __builtin_amdgcn_mbcnt_lo((unsigned)b2, 0));
    off    += __builtin_amdgcn_mbcnt_hi((unsigned)(b3 >> 32),
              __builtin_amdgcn_mbcnt_lo((unsigned)b3, 0));
    const int M = __popcll(b1) + __popcll(b2) + __popcll(b3);

    if (cnt >= 1 && off     < NTAPS) amb_lds[wave][off]     = za;
    if (cnt >= 2 && off + 1 < NTAPS) amb_lds[wave][off + 1] = zb;
    if (cnt >= 3 && off + 2 < NTAPS) amb_lds[wave][off + 2] = zc;
    asm volatile("s_waitcnt lgkmcnt(0)" ::: "memory");

    const bool fast_ok = (b4 == 0ULL) && (M <= NTAPS);

    float lo = Lo, hi = Hi;
    const float ucut = MAX_W - EPS;
    float tau, tau0;
    int nf_total;

    if (fast_ok) {
        // Hoist up to NTAPS taps (12 packed pairs); absent -> Lo.
        f32x2 a2[NTAPS / 2];
        #pragma unroll
        for (int i = 0; i < NTAPS / 2; ++i) {
            a2[i].x = (2*i     < M) ? amb_lds[wave][2*i]     : Lo;
            a2[i].y = (2*i + 1 < M) ? amb_lds[wave][2*i + 1] : Lo;
        }
        // 64-way multisection: s(tl) = capC + sum clip(a - tl); one ballot/round.
        #pragma unroll
        for (int r = 0; r < MS_ROUNDS; ++r) {
            const float step = (hi - lo) * 0.015625f;
            const float tl = fmaf((float)(lane + 1), step, lo);
            f32x2 ntl; ntl.x = -tl; ntl.y = -tl;
            f32x2 acc0 = {0.f, 0.f}, acc1 = {0.f, 0.f};
            #pragma unroll
            for (int i = 0; i < NTAPS / 2; i += 2) {
                f32x2 t0, t1;
                PKADD(t0, a2[i],   ntl);
                PKADD(t1, a2[i+1], ntl);
                t0.x = clipu(t0.x); t0.y = clipu(t0.y);
                t1.x = clipu(t1.x); t1.y = clipu(t1.y);
                PKADD(acc0, acc0, t0);
                PKADD(acc1, acc1, t1);
            }
            PKADD(acc0, acc0, acc1);
            const float s = capC + (acc0.x + acc0.y);
            const unsigned long long mask = __ballot(s > 1.0f);
            int j = __popcll(mask);
            j = (j > 63) ? 63 : j;
            const float lo_old = lo;
            lo = fmaf((float)j, step, lo_old);
            hi = fmaf((float)(j + 1), step, lo_old);
        }
        tau0 = 0.5f * (lo + hi);

        // ---- Epilogue over the taps only (wave-uniform, no reduces) ----
        int nf = 0, ncap = capcnt;
        float sfree = 0.0f;
        #pragma unroll
        for (int i = 0; i < NTAPS / 2; ++i) {
            const float w0x = clipu(a2[i].x - tau0);
            const float w0y = clipu(a2[i].y - tau0);
            const bool fx = (w0x > EPS) && (w0x < ucut);
            const bool fy = (w0y > EPS) && (w0y < ucut);
            nf += fx ? 1 : 0;          nf += fy ? 1 : 0;
            sfree += fx ? a2[i].x : 0.0f;
            sfree += fy ? a2[i].y : 0.0f;
            ncap += (w0x >= ucut) ? 1 : 0;
            ncap += (w0y >= ucut) ? 1 : 0;
        }
        nf_total = nf;
        tau = (sfree + MAX_W * (float)ncap - 1.0f) / fmaxf((float)nf, 1.0f);
    } else {
        // ---- Fallback: sum-scan bisection on [Lo, Hi] ----
        for (int it = 0; it < FB_ITERS; ++it) {
            const float mid = 0.5f * (lo + hi);
            const float s = wave_sum(scan_sum(zp, mid));
            const bool too_big = s > 1.0f;
            lo = too_big ? mid : lo;
            hi = too_big ? hi : mid;
        }
        tau0 = 0.5f * (lo + hi);
        // Full active-set pass (per-lane counts + reduces).
        f32x2 nt0; nt0.x = -tau0; nt0.y = -tau0;
        float sf0 = 0.0f, sf1 = 0.0f;
        int nf_i = 0, nc_i = 0;
        #pragma unroll
        for (int k = 0; k < 32; k += 2) {
            f32x2 t0, t1;
            PKADD(t0, zp[k],   nt0);
            PKADD(t1, zp[k+1], nt0);
            const float wa = clipu(t0.x), wb = clipu(t0.y);
            const float wc = clipu(t1.x), wd = clipu(t1.y);
            const bool fa = (wa > EPS) && (wa < ucut);
            const bool fb = (wb > EPS) && (wb < ucut);
            const bool fc = (wc > EPS) && (wc < ucut);
            const bool fd = (wd > EPS) && (wd < ucut);
            sf0 += fa ? zp[k].x   : 0.0f;
            sf1 += fb ? zp[k].y   : 0.0f;
            sf0 += fc ? zp[k+1].x : 0.0f;
            sf1 += fd ? zp[k+1].y : 0.0f;
            nf_i += (fa ? 1 : 0) + (fb ? 1 : 0) + (fc ? 1 : 0) + (fd ? 1 : 0);
            nc_i += (wa >= ucut) + (wb >= ucut) + (wc >= ucut) + (wd >= ucut);
        }
        const float s_free = wave_sum(sf0 + sf1);
        nf_i = wave_isum(nf_i);
        nc_i = wave_isum(nc_i);
        nf_total = nf_i;
        tau = (s_free + MAX_W * (float)nc_i - 1.0f) / fmaxf((float)nf_i, 1.0f);
    }

    if (nf_total > 0) {
        // ---- Fast final write: med3(z - tau, 0, u), non-temporal stores ----
        f32x2 ntau; ntau.x = -tau; ntau.y = -tau;
        #pragma unroll
        for (int k = 0; k < 16; ++k) {
            f32x2 t0, t1;
            PKADD(t0, zp[2*k],   ntau);
            PKADD(t1, zp[2*k+1], ntau);
            f32x4 o;
            o.x = clipu(t0.x); o.y = clipu(t0.y);
            o.z = clipu(t1.x); o.w = clipu(t1.y);
            __builtin_nontemporal_store(o, &outr[k * 64 + lane]);
        }
    } else {
        // ---- n_free == 0: reference ignores its tau; classification write ----
        const float capAt0 = tau0 + ucut;
        #pragma unroll
        for (int k = 0; k < 16; ++k) {
            f32x4 o;
            o.x = (zp[2*k].x   >= capAt0) ? MAX_W : 0.0f;
            o.y = (zp[2*k].y   >= capAt0) ? MAX_W : 0.0f;
            o.z = (zp[2*k+1].x >= capAt0) ? MAX_W : 0.0f;
            o.w = (zp[2*k+1].y >= capAt0) ? MAX_W : 0.0f;
            __builtin_nontemporal_store(o, &outr[k * 64 + lane]);
        }
    }
}

extern "C" void kernel_launch(void* const* d_in, const int* in_sizes, int n_in,
                              void* d_out, int out_size, void* d_ws, size_t ws_size,
                              hipStream_t stream) {
    const float* x    = (const float*)d_in[0];
    const float* temp = (const float*)d_in[1];
    float* out = (float*)d_out;
    (void)in_sizes; (void)n_in; (void)out_size; (void)d_ws; (void)ws_size;

    dim3 grid(N_SAMPLES / 4);   // 4 rows (waves) per 256-thread block
    dim3 block(256);
    hipLaunchKernelGGL(sparsemax_alloc_kernel, grid, block, 0, stream, x, temp, out);
}

// Round 12
// 78.062 us; speedup vs baseline: 1.6754x; 1.0760x over previous
//
#include <hip/hip_runtime.h>

// Capped simplex projection: per row, w = clip(z - tau, 0, u), sum(w) = 1.
// One wave (64 lanes) per row; 64 fp32 elements per lane in registers.
//
// R11 changes vs R10 (single-scan band compaction):
//  - The probe scan now ALSO compacts all elements in (t1-u, t2+u] (expected
//    ~50) into per-lane-private LDS slots (6/lane) and counts cBH = #{z>bandHi}.
//  - All subsequent global counts are band-local: count(t) = cBH + #{band>t}
//    via 6 register compares + 1 DPP isum (24 insts vs 270 full scan).
//    c1/c2 derived from the same regs (one packed isum). 10 fixed bisect iters.
//  - Classify full pass deleted: taps = band regs in (Lo, capTh); capcnt =
//    c_chi - #{band in (chi, capTh)} (c_chi tracked through bisection).
//  - MS 3 rounds / epilogue / writes identical to R10 (tau0 err ~8e-8 kept
//    for the n_free==0 classification write).
//  - Fallbacks (probe mis-bracket / lane>6 band / taps>24): full sum-scan
//    bisection from a valid bracket + full epilogue. Correct for any data.

#define N_ASSETS 4096
#define N_SAMPLES 16384
#define MAX_W 0.02f
#define EPS 1e-7f
#define KRANK 50             // ceil(1 / MAX_W)
#define FB_ITERS 17          // fallback sum-scan iterations
#define MS_ROUNDS 3          // multisection rounds (6 bits each)
#define NTAPS 24
#define BB_ITERS 10          // band-local bisect iterations
#define T1MULT 2.09f
#define T2MULT 2.41f

typedef __attribute__((ext_vector_type(2))) float f32x2;
typedef __attribute__((ext_vector_type(4))) float f32x4;

#define PKADD(d, a, b) asm("v_pk_add_f32 %0, %1, %2" : "=v"(d) : "v"(a), "v"(b))
#define PKMUL(d, a, b) asm("v_pk_mul_f32 %0, %1, %2" : "=v"(d) : "v"(a), "v"(b))
#define PKFMA(d, a, b, c) asm("v_pk_fma_f32 %0, %1, %2, %3" : "=v"(d) : "v"(a), "v"(b), "v"(c))

__device__ __forceinline__ float clipu(float v) {
    return __builtin_amdgcn_fmed3f(v, 0.0f, MAX_W);
}
__device__ __forceinline__ float bc_int_as_f(int v) {
    union { int i; float f; } u; u.i = v; return u.f;
}
__device__ __forceinline__ int bc_f_as_int(float v) {
    union { int i; float f; } u; u.f = v; return u.i;
}

template <int CTRL, int RMASK, bool BC>
__device__ __forceinline__ float dpp_add_step(float x) {
    int t = __builtin_amdgcn_update_dpp(0, bc_f_as_int(x), CTRL, RMASK, 0xF, BC);
    return x + bc_int_as_f(t);
}
__device__ __forceinline__ float wave_sum(float v) {
    v = dpp_add_step<0x111, 0xF, true>(v);
    v = dpp_add_step<0x112, 0xF, true>(v);
    v = dpp_add_step<0x114, 0xF, true>(v);
    v = dpp_add_step<0x118, 0xF, true>(v);
    v = dpp_add_step<0x142, 0xA, false>(v);
    v = dpp_add_step<0x143, 0xC, false>(v);
    return bc_int_as_f(__builtin_amdgcn_readlane(bc_f_as_int(v), 63));
}
template <int CTRL, int RMASK, bool BC>
__device__ __forceinline__ int dpp_iadd_step(int x) {
    int t = __builtin_amdgcn_update_dpp(0, x, CTRL, RMASK, 0xF, BC);
    return x + t;
}
__device__ __forceinline__ int wave_isum(int v) {
    v = dpp_iadd_step<0x111, 0xF, true>(v);
    v = dpp_iadd_step<0x112, 0xF, true>(v);
    v = dpp_iadd_step<0x114, 0xF, true>(v);
    v = dpp_iadd_step<0x118, 0xF, true>(v);
    v = dpp_iadd_step<0x142, 0xA, false>(v);
    v = dpp_iadd_step<0x143, 0xC, false>(v);
    return __builtin_amdgcn_readlane(v, 63);
}
template <int CTRL, int RMASK>
__device__ __forceinline__ float dpp_min_step(float x) {
    int xi = bc_f_as_int(x);
    int t = __builtin_amdgcn_update_dpp(xi, xi, CTRL, RMASK, 0xF, false);
    return fminf(x, bc_int_as_f(t));
}
template <int CTRL, int RMASK>
__device__ __forceinline__ float dpp_max_step(float x) {
    int xi = bc_f_as_int(x);
    int t = __builtin_amdgcn_update_dpp(xi, xi, CTRL, RMASK, 0xF, false);
    return fmaxf(x, bc_int_as_f(t));
}
__device__ __forceinline__ float wave_min(float v) {
    v = dpp_min_step<0x111, 0xF>(v); v = dpp_min_step<0x112, 0xF>(v);
    v = dpp_min_step<0x114, 0xF>(v); v = dpp_min_step<0x118, 0xF>(v);
    v = dpp_min_step<0x142, 0xA>(v); v = dpp_min_step<0x143, 0xC>(v);
    return bc_int_as_f(__builtin_amdgcn_readlane(bc_f_as_int(v), 63));
}
__device__ __forceinline__ float wave_max(float v) {
    v = dpp_max_step<0x111, 0xF>(v); v = dpp_max_step<0x112, 0xF>(v);
    v = dpp_max_step<0x114, 0xF>(v); v = dpp_max_step<0x118, 0xF>(v);
    v = dpp_max_step<0x142, 0xA>(v); v = dpp_max_step<0x143, 0xC>(v);
    return bc_int_as_f(__builtin_amdgcn_readlane(bc_f_as_int(v), 63));
}

// Full packed scan: sum of clip(z - mid) over 32 pairs (fallback path only).
__device__ __forceinline__ float scan_sum(const f32x2* zp, float mid) {
    f32x2 nm; nm.x = -mid; nm.y = -mid;
    f32x2 acc0 = {0.f, 0.f}, acc1 = {0.f, 0.f}, acc2 = {0.f, 0.f}, acc3 = {0.f, 0.f};
    #pragma unroll
    for (int k = 0; k < 32; k += 4) {
        f32x2 t0, t1, t2, t3;
        PKADD(t0, zp[k+0], nm);
        PKADD(t1, zp[k+1], nm);
        PKADD(t2, zp[k+2], nm);
        PKADD(t3, zp[k+3], nm);
        t0.x = clipu(t0.x); t0.y = clipu(t0.y);
        t1.x = clipu(t1.x); t1.y = clipu(t1.y);
        t2.x = clipu(t2.x); t2.y = clipu(t2.y);
        t3.x = clipu(t3.x); t3.y = clipu(t3.y);
        PKADD(acc0, acc0, t0);
        PKADD(acc1, acc1, t1);
        PKADD(acc2, acc2, t2);
        PKADD(acc3, acc3, t3);
    }
    PKADD(acc0, acc0, acc1);
    PKADD(acc2, acc2, acc3);
    PKADD(acc0, acc0, acc2);
    return acc0.x + acc0.y;
}

__global__ __launch_bounds__(256) void sparsemax_alloc_kernel(
    const float* __restrict__ x,
    const float* __restrict__ temperature,
    float* __restrict__ out) {

    __shared__ float band_lds[4][64][6];
    __shared__ float amb_lds[4][NTAPS];

    const int wave = threadIdx.x >> 6;          // 4 waves per block
    const int lane = threadIdx.x & 63;
    const int row  = blockIdx.x * 4 + wave;

    const float4* xr   = reinterpret_cast<const float4*>(x + (size_t)row * N_ASSETS);
    f32x4*        outr = reinterpret_cast<f32x4*>(out + (size_t)row * N_ASSETS);

    const float rt = 1.0f / temperature[row];
    f32x2 rt2; rt2.x = rt; rt2.y = rt;

    // ---- Load + fused stats (min/max/sum z^2) ----
    f32x2 zp[32];
    float mn = 3.4e38f, mx = -3.4e38f;
    f32x2 ss0 = {0.f, 0.f}, ss1 = {0.f, 0.f};
    #pragma unroll
    for (int k = 0; k < 16; ++k) {
        float4 v = xr[k * 64 + lane];
        f32x2 lohalf, hihalf;
        lohalf.x = v.x; lohalf.y = v.y;
        hihalf.x = v.z; hihalf.y = v.w;
        PKMUL(zp[2*k],   lohalf, rt2);
        PKMUL(zp[2*k+1], hihalf, rt2);
        mn = fminf(mn, fminf(zp[2*k].x,   zp[2*k].y));
        mx = fmaxf(mx, fmaxf(zp[2*k].x,   zp[2*k].y));
        mn = fminf(mn, fminf(zp[2*k+1].x, zp[2*k+1].y));
        mx = fmaxf(mx, fmaxf(zp[2*k+1].x, zp[2*k+1].y));
        PKFMA(ss0, zp[2*k],   zp[2*k],   ss0);
        PKFMA(ss1, zp[2*k+1], zp[2*k+1], ss1);
    }
    mn = wave_min(mn);
    mx = wave_max(mx);
    PKADD(ss0, ss0, ss1);
    const float sig = sqrtf(wave_sum(ss0.x + ss0.y) * (1.0f / (float)N_ASSETS));

    const float t1 = T1MULT * sig;
    const float t2 = T2MULT * sig;
    const float bandLo = t1 - MAX_W;
    const float bandHi = t2 + MAX_W;

    // ---- Probe scan: count cBH = #{z > bandHi}; scatter band elements ----
    float* slots = &band_lds[wave][lane][0];
    #pragma unroll
    for (int i = 0; i < 6; ++i) slots[i] = bandLo;   // sentinel

    int cBH = 0, bcnt = 0;
    #pragma unroll
    for (int k = 0; k < 32; ++k) {
        #pragma unroll
        for (int c = 0; c < 2; ++c) {
            const float v = (c == 0) ? zp[k].x : zp[k].y;
            const bool hiB = v > bandHi;
            cBH += hiB ? 1 : 0;
            const bool inB = (v > bandLo) && !hiB;
            if (inB) {
                slots[bcnt < 6 ? bcnt : 5] = v;
                ++bcnt;
            }
        }
    }
    asm volatile("s_waitcnt lgkmcnt(0)" ::: "memory");
    const float e0 = slots[0], e1 = slots[1], e2 = slots[2];
    const float e3 = slots[3], e4 = slots[4], e5 = slots[5];

    // Packed reduce: cBH (13b) | #{band>t1} (10b) | #{band>t2} (9b).
    int cg1 = (e0 > t1) + (e1 > t1) + (e2 > t1) + (e3 > t1) + (e4 > t1) + (e5 > t1);
    int cg2 = (e0 > t2) + (e1 > t2) + (e2 > t2) + (e3 > t2) + (e4 > t2) + (e5 > t2);
    const unsigned sred = (unsigned)wave_isum(cBH | (cg1 << 13) | (cg2 << 23));
    const int cBHt = (int)(sred & 0x1FFFu);
    const int c1   = cBHt + (int)((sred >> 13) & 0x3FFu);
    const int c2   = cBHt + (int)(sred >> 23);

    const bool ovf = __ballot(bcnt >= 7) != 0ULL;
    bool fastpath = (c1 >= KRANK) && (c2 < KRANK) && !ovf;

    float fbLo = mn - 1.0f, fbHi = mx;   // always-valid fallback bracket
    float tau = 0.0f, tau0 = 0.0f;
    int nf_total = 0;
    const float ucut = MAX_W - EPS;

    if (fastpath) {
        // ---- Band-local count bisection (all counts from 6 regs) ----
        float clo = t1, chi = t2;
        int c_chi = c2;
        #pragma unroll
        for (int it = 0; it < BB_ITERS; ++it) {
            const float mid = 0.5f * (clo + chi);
            int pc = (e0 > mid) + (e1 > mid) + (e2 > mid)
                   + (e3 > mid) + (e4 > mid) + (e5 > mid);
            const int cc = cBHt + wave_isum(pc);
            const bool big = (cc >= KRANK);
            clo = big ? mid : clo;
            chi = big ? chi : mid;
            c_chi = big ? c_chi : cc;
        }
        const float Lo = clo - MAX_W;
        const float Hi = chi;
        const float capTh = Hi + MAX_W;

        // ---- Taps from band regs: elements in (Lo, capTh) ----
        float za = Lo, zb = Lo, zc = Lo;
        int tcnt = 0;
        {
            const float ee[6] = {e0, e1, e2, e3, e4, e5};
            #pragma unroll
            for (int i = 0; i < 6; ++i) {
                const bool tap = (ee[i] > Lo) && (ee[i] < capTh);
                za = (tap && tcnt == 0) ? ee[i] : za;
                zb = (tap && tcnt == 1) ? ee[i] : zb;
                zc = (tap && tcnt == 2) ? ee[i] : zc;
                tcnt += tap ? 1 : 0;
            }
        }
        const unsigned long long b1 = __ballot(tcnt >= 1);
        const unsigned long long b2 = __ballot(tcnt >= 2);
        const unsigned long long b3 = __ballot(tcnt >= 3);
        const unsigned long long b4 = __ballot(tcnt >= 4);
        int off = __builtin_amdgcn_mbcnt_hi((unsigned)(b1 >> 32),
                  __builtin_amdgcn_mbcnt_lo((unsigned)b1, 0));
        off    += __builtin_amdgcn_mbcnt_hi((unsigned)(b2 >> 32),
                  __builtin_amdgcn_mbcnt_lo((unsigned)b2, 0));
        off    += __builtin_amdgcn_mbcnt_hi((unsigned)(b3 >> 32),
                  __builtin_amdgcn_mbcnt_lo((unsigned)b3, 0));
        const int M = __popcll(b1) + __popcll(b2) + __popcll(b3);

        if (tcnt >= 1 && off     < NTAPS) amb_lds[wave][off]     = za;
        if (tcnt >= 2 && off + 1 < NTAPS) amb_lds[wave][off + 1] = zb;
        if (tcnt >= 3 && off + 2 < NTAPS) amb_lds[wave][off + 2] = zc;
        asm volatile("s_waitcnt lgkmcnt(0)" ::: "memory");

        if ((b4 != 0ULL) || (M > NTAPS)) {
            fastpath = false;            // rare: taps overflow -> tight FB bracket
            fbLo = Lo; fbHi = Hi;
        } else {
            // capcnt = #{z >= capTh} = c_chi - #{band in (chi, capTh)}
            int pcc = ((e0 > chi) && (e0 < capTh)) + ((e1 > chi) && (e1 < capTh))
                    + ((e2 > chi) && (e2 < capTh)) + ((e3 > chi) && (e3 < capTh))
                    + ((e4 > chi) && (e4 < capTh)) + ((e5 > chi) && (e5 < capTh));
            const int capcnt = c_chi - wave_isum(pcc);
            const float capC = (float)capcnt * MAX_W;

            // ---- 64-way multisection over taps (closed form) ----
            f32x2 a2[NTAPS / 2];
            #pragma unroll
            for (int i = 0; i < NTAPS / 2; ++i) {
                a2[i].x = (2*i     < M) ? amb_lds[wave][2*i]     : Lo;
                a2[i].y = (2*i + 1 < M) ? amb_lds[wave][2*i + 1] : Lo;
            }
            float lo = Lo, hi = Hi;
            #pragma unroll
            for (int r = 0; r < MS_ROUNDS; ++r) {
                const float step = (hi - lo) * 0.015625f;
                const float tl = fmaf((float)(lane + 1), step, lo);
                f32x2 ntl; ntl.x = -tl; ntl.y = -tl;
                f32x2 acc0 = {0.f, 0.f}, acc1 = {0.f, 0.f};
                #pragma unroll
                for (int i = 0; i < NTAPS / 2; i += 2) {
                    f32x2 q0, q1;
                    PKADD(q0, a2[i],   ntl);
                    PKADD(q1, a2[i+1], ntl);
                    q0.x = clipu(q0.x); q0.y = clipu(q0.y);
                    q1.x = clipu(q1.x); q1.y = clipu(q1.y);
                    PKADD(acc0, acc0, q0);
                    PKADD(acc1, acc1, q1);
                }
                PKADD(acc0, acc0, acc1);
                const float s = capC + (acc0.x + acc0.y);
                const unsigned long long mask = __ballot(s > 1.0f);
                int j = __popcll(mask);
                j = (j > 63) ? 63 : j;
                const float lo_old = lo;
                lo = fmaf((float)j, step, lo_old);
                hi = fmaf((float)(j + 1), step, lo_old);
            }
            tau0 = 0.5f * (lo + hi);

            // ---- Epilogue over taps (wave-uniform) ----
            int nf = 0, ncap = capcnt;
            float sfree = 0.0f;
            #pragma unroll
            for (int i = 0; i < NTAPS / 2; ++i) {
                const float w0x = clipu(a2[i].x - tau0);
                const float w0y = clipu(a2[i].y - tau0);
                const bool fx = (w0x > EPS) && (w0x < ucut);
                const bool fy = (w0y > EPS) && (w0y < ucut);
                nf += fx ? 1 : 0;          nf += fy ? 1 : 0;
                sfree += fx ? a2[i].x : 0.0f;
                sfree += fy ? a2[i].y : 0.0f;
                ncap += (w0x >= ucut) ? 1 : 0;
                ncap += (w0y >= ucut) ? 1 : 0;
            }
            nf_total = nf;
            tau = (sfree + MAX_W * (float)ncap - 1.0f) / fmaxf((float)nf, 1.0f);
        }
    }

    if (!fastpath) {
        // ---- Fallback: sum-scan bisection from a valid bracket ----
        float lo = fbLo, hi = fbHi;
        for (int it = 0; it < FB_ITERS; ++it) {
            const float mid = 0.5f * (lo + hi);
            const float s = wave_sum(scan_sum(zp, mid));
            const bool too_big = s > 1.0f;
            lo = too_big ? mid : lo;
            hi = too_big ? hi : mid;
        }
        tau0 = 0.5f * (lo + hi);
        // Full active-set pass.
        f32x2 nt0; nt0.x = -tau0; nt0.y = -tau0;
        float sf0 = 0.0f, sf1 = 0.0f;
        int nf_i = 0, nc_i = 0;
        #pragma unroll
        for (int k = 0; k < 32; k += 2) {
            f32x2 q0, q1;
            PKADD(q0, zp[k],   nt0);
            PKADD(q1, zp[k+1], nt0);
            const float wa = clipu(q0.x), wb = clipu(q0.y);
            const float wc = clipu(q1.x), wd = clipu(q1.y);
            const bool fa = (wa > EPS) && (wa < ucut);
            const bool fb = (wb > EPS) && (wb < ucut);
            const bool fc = (wc > EPS) && (wc < ucut);
            const bool fd = (wd > EPS) && (wd < ucut);
            sf0 += fa ? zp[k].x   : 0.0f;
            sf1 += fb ? zp[k].y   : 0.0f;
            sf0 += fc ? zp[k+1].x : 0.0f;
            sf1 += fd ? zp[k+1].y : 0.0f;
            nf_i += (fa ? 1 : 0) + (fb ? 1 : 0) + (fc ? 1 : 0) + (fd ? 1 : 0);
            nc_i += (wa >= ucut) + (wb >= ucut) + (wc >= ucut) + (wd >= ucut);
        }
        const float s_free = wave_sum(sf0 + sf1);
        nf_i = wave_isum(nf_i);
        nc_i = wave_isum(nc_i);
        nf_total = nf_i;
        tau = (s_free + MAX_W * (float)nc_i - 1.0f) / fmaxf((float)nf_i, 1.0f);
    }

    if (nf_total > 0) {
        // ---- Fast final write: med3(z - tau, 0, u), non-temporal ----
        f32x2 ntau; ntau.x = -tau; ntau.y = -tau;
        #pragma unroll
        for (int k = 0; k < 16; ++k) {
            f32x2 q0, q1;
            PKADD(q0, zp[2*k],   ntau);
            PKADD(q1, zp[2*k+1], ntau);
            f32x4 o;
            o.x = clipu(q0.x); o.y = clipu(q0.y);
            o.z = clipu(q1.x); o.w = clipu(q1.y);
            __builtin_nontemporal_store(o, &outr[k * 64 + lane]);
        }
    } else {
        // ---- n_free == 0: classification write (reference ignores its tau) ----
        const float capAt0 = tau0 + ucut;
        #pragma unroll
        for (int k = 0; k < 16; ++k) {
            f32x4 o;
            o.x = (zp[2*k].x   >= capAt0) ? MAX_W : 0.0f;
            o.y = (zp[2*k].y   >= capAt0) ? MAX_W : 0.0f;
            o.z = (zp[2*k+1].x >= capAt0) ? MAX_W : 0.0f;
            o.w = (zp[2*k+1].y >= capAt0) ? MAX_W : 0.0f;
            __builtin_nontemporal_store(o, &outr[k * 64 + lane]);
        }
    }
}

extern "C" void kernel_launch(void* const* d_in, const int* in_sizes, int n_in,
                              void* d_out, int out_size, void* d_ws, size_t ws_size,
                              hipStream_t stream) {
    const float* x    = (const float*)d_in[0];
    const float* temp = (const float*)d_in[1];
    float* out = (float*)d_out;
    (void)in_sizes; (void)n_in; (void)out_size; (void)d_ws; (void)ws_size;

    dim3 grid(N_SAMPLES / 4);   // 4 rows (waves) per 256-thread block
    dim3 block(256);
    hipLaunchKernelGGL(sparsemax_alloc_kernel, grid, block, 0, stream, x, temp, out);
}